// Round 4
// baseline (142.869 us; speedup 1.0000x reference)
//
#include <hip/hip_runtime.h>
#include <cstdint>
#include <cstdio>

// ---------------------------------------------------------------------------
// TransConvLayer (linear attention) for MI355X / gfx950 — Round 3.
//
// ALGORITHM (exact to O(1e-9) rel, see journal):
//   S = 1/(||Q||_F ||K||_F) ~ 5.9e-8 folds out both global normalizations:
//     out[n,d] = mean_h (S*(q.kvs_raw) + N*v) / (S*(q.ksum_raw) + N)
//              = mean_h v[n,h,d] + O(1e-9)      (threshold 2.19e-2)
//   and mean_h v collapses into ONE GEMM:
//     out = X_s @ Wmean + bmean,  Wmean[k][d] = (1/8) sum_h Wv[k][h*128+d].
//
// DTYPE RESOLUTION (round-2 post-mortem): inputs AND output are fp32,
//   exactly as the reference declares.
//   - r1 (fp32 in, bf16-ushort out) -> finite 1.449: bf16 pairs read as fp32.
//   - r2 (bf16 in) -> NaN: fp32 low-halves as bf16 hit exponent 0xFF with
//     P=1/256 -> ~50k NaNs in 12.8M staged elements. QED.
//   This round: fp32 loads (convert to bf16 in staging), fp32 stores.
//
// K1 fold_w : Wmean -> bf16, stored TRANSPOSED WtB[d][k]; bmean[128] fp32.
// K2 gemm_out: [50000x256]@[256x128], bf16 MFMA, fp32 accumulate/store.
// Roofline: 52MB read + 25.6MB write ~ 12.4us at 6.3TB/s.
// ---------------------------------------------------------------------------

#define N_NODES 50000
#define IN_CH   256
#define HD      1024
#define HEADS   8
#define DH      128
#define LDS_K   72          // 64 + 8 bf16 pad: 2-way bank aliasing only (free)

typedef __attribute__((ext_vector_type(8))) short   shortx8;
typedef __attribute__((ext_vector_type(4))) float   floatx4;

__device__ __forceinline__ unsigned short f2b(float f) {
  unsigned int u = __float_as_uint(f);
  u += 0x7FFFu + ((u >> 16) & 1u);   // round-nearest-even
  return (unsigned short)(u >> 16);
}

// ---------------- K1: fold Wv across heads, transpose, cast bf16 -----------
// WtB[d][k] = f2b( (1/8) sum_h Wv[k][h*128+d] ),  bmean[d] = (1/8) sum_h bv[.]
__global__ __launch_bounds__(256) void fold_w(
    const float* __restrict__ Wv, const float* __restrict__ bv,
    unsigned short* __restrict__ WtB, float* __restrict__ bmean)
{
  int idx = blockIdx.x * 256 + threadIdx.x;    // 32768 = 256k x 128d
  int k = idx >> 7;
  int d = idx & 127;
  float s = 0.f;
  #pragma unroll
  for (int h = 0; h < HEADS; ++h) s += Wv[(size_t)k * HD + h * DH + d];
  WtB[d * IN_CH + k] = f2b(0.125f * s);
  if (idx < DH) {
    float b = 0.f;
    #pragma unroll
    for (int h = 0; h < HEADS; ++h) b += bv[h * DH + idx];
    bmean[idx] = 0.125f * b;
  }
}

// ---------------- K2: out = X_s @ Wmean + bmean ----------------------------
// grid.x = 391 (128-row tiles), 256 threads = 4 waves in 2x2 of 64x64.
__global__ __launch_bounds__(256) void gemm_out(
    const float* __restrict__ X, const unsigned short* __restrict__ WtB,
    const float* __restrict__ bmean, float* __restrict__ out)
{
  const int m0   = blockIdx.x * 128;
  const int tid  = threadIdx.x;
  const int wave = tid >> 6, lane = tid & 63;
  const int quad = lane >> 4, l15 = lane & 15;
  const int wr   = (wave >> 1) * 64;     // wave's row offset in tile
  const int wc   = (wave & 1) * 64;      // wave's col offset

  __shared__ __align__(16) unsigned short As[128 * LDS_K];  // X tile -> bf16
  __shared__ __align__(16) unsigned short Bs[128 * LDS_K];  // Wmean^T chunk

  floatx4 acc[4][4];
  #pragma unroll
  for (int a = 0; a < 4; ++a)
    #pragma unroll
    for (int b = 0; b < 4; ++b) acc[a][b] = (floatx4){0.f, 0.f, 0.f, 0.f};

  for (int k0 = 0; k0 < IN_CH; k0 += 64) {
    __syncthreads();
    // Stage A (128 rows x 64 k, fp32 -> bf16, 32B/thread contiguous reads)
    // and B (128 d x 64 k, bf16 16B/thread).
    #pragma unroll
    for (int i = 0; i < 4; ++i) {
      int e   = i * 2048 + tid * 8;
      int row = e >> 6;           // 0..127 (A-row / B-d)
      int kk  = e & 63;
      int node = m0 + row;
      float4 x0 = make_float4(0.f, 0.f, 0.f, 0.f);
      float4 x1 = make_float4(0.f, 0.f, 0.f, 0.f);
      if (node < N_NODES) {
        const float* p = X + (size_t)node * IN_CH + k0 + kk;
        x0 = *(const float4*)p;
        x1 = *(const float4*)(p + 4);
      }
      unsigned short t8[8] = {f2b(x0.x), f2b(x0.y), f2b(x0.z), f2b(x0.w),
                              f2b(x1.x), f2b(x1.y), f2b(x1.z), f2b(x1.w)};
      *(uint4*)&As[row * LDS_K + kk] = *(const uint4*)t8;
      *(uint4*)&Bs[row * LDS_K + kk] =
          *(const uint4*)(WtB + (size_t)row * IN_CH + k0 + kk);
    }
    __syncthreads();

    #pragma unroll
    for (int ks = 0; ks < 2; ++ks) {     // two K=32 MFMA steps per chunk
      shortx8 af[4], bf[4];
      #pragma unroll
      for (int t = 0; t < 4; ++t)
        af[t] = *(const shortx8*)&As[(wr + t * 16 + l15) * LDS_K + ks * 32 + quad * 8];
      #pragma unroll
      for (int t = 0; t < 4; ++t)
        bf[t] = *(const shortx8*)&Bs[(wc + t * 16 + l15) * LDS_K + ks * 32 + quad * 8];
      #pragma unroll
      for (int tm = 0; tm < 4; ++tm)
        #pragma unroll
        for (int tn = 0; tn < 4; ++tn)
          acc[tm][tn] = __builtin_amdgcn_mfma_f32_16x16x32_bf16(
              af[tm], bf[tn], acc[tm][tn], 0, 0, 0);
    }
  }

  // Epilogue: + bmean, fp32 store.
  // C/D layout (m89-verified): col = lane&15, row = quad*4 + reg.
  #pragma unroll
  for (int tm = 0; tm < 4; ++tm) {
    #pragma unroll
    for (int tn = 0; tn < 4; ++tn) {
      int d = wc + tn * 16 + l15;
      float bm = bmean[d];
      #pragma unroll
      for (int r = 0; r < 4; ++r) {
        int node = m0 + wr + tm * 16 + quad * 4 + r;
        if (node < N_NODES)
          out[(size_t)node * DH + d] = acc[tm][tn][r] + bm;
      }
    }
  }
}

// ---------------- host ----------------
extern "C" void kernel_launch(void* const* d_in, const int* in_sizes, int n_in,
                              void* d_out, int out_size, void* d_ws, size_t ws_size,
                              hipStream_t stream) {
  const float* Xs = (const float*)d_in[1];   // source_input [50000][256] fp32
  const float* Wv = (const float*)d_in[6];   // Wv_w [256][1024] fp32
  const float* bv = (const float*)d_in[7];   // Wv_b [1024] fp32

  char* ws = (char*)d_ws;
  unsigned short* WtB   = (unsigned short*)(ws);            // 64 KB
  float*          bmean = (float*)(ws + 65536);             // 512 B

  if (ws_size < 66048) {
    fprintf(stderr, "[TransConv] ws_size=%zu too small\n", ws_size);
    return;
  }

  fold_w<<<128, 256, 0, stream>>>(Wv, bv, WtB, bmean);
  gemm_out<<<391, 256, 0, stream>>>(Xs, WtB, bmean, (float*)d_out);
}

// Round 5
// 137.146 us; speedup vs baseline: 1.0417x; 1.0417x over previous
//
#include <hip/hip_runtime.h>
#include <cstdint>
#include <cstdio>

// ---------------------------------------------------------------------------
// TransConvLayer (linear attention) for MI355X / gfx950 — Round 4.
//
// ALGORITHM (exact to O(1e-9) rel; validated round 3, absmax 3.9e-3):
//   S = 1/(||Q||_F ||K||_F) ~ 5.9e-8 folds out both global normalizations:
//     out[n,d] = mean_h (S*(q.kvs_raw) + N*v) / (S*(q.ksum_raw) + N)
//              = mean_h v[n,h,d] + O(1e-9)
//   mean_h v collapses into ONE GEMM:
//     out = X_s @ Wmean + bmean,  Wmean[k][d] = (1/8) sum_h Wv[k][h*128+d].
//   fp32 in / fp32 out; bf16 MFMA with fp32 accumulation internally.
//
// ROUND-4 CHANGE (load-balance experiment): 64-row tiles, 782 blocks
//   (vs 391x128): round-3's tail phase left only ~135 CUs streaming at
//   ~24 GB/s/CU = 3.2 TB/s (half of achievable BW). Finer quanta shrink
//   the tail to ~14 tiles. Predicted gemm ~16 -> ~13 us. dur_us is
//   dominated by harness d_ws re-poison (41 us fills at 80% HBM peak in
//   rocprof) + input restores — those are invariant; this round measures
//   exactly how much of dur_us is ours.
// ---------------------------------------------------------------------------

#define N_NODES 50000
#define IN_CH   256
#define HD      1024
#define HEADS   8
#define DH      128
#define LDS_K   72   // 64 + 8 bf16 pad; rows stay 16B-aligned (144 B stride)

typedef __attribute__((ext_vector_type(8))) short   shortx8;
typedef __attribute__((ext_vector_type(4))) float   floatx4;

__device__ __forceinline__ unsigned short f2b(float f) {
  unsigned int u = __float_as_uint(f);
  u += 0x7FFFu + ((u >> 16) & 1u);   // round-nearest-even
  return (unsigned short)(u >> 16);
}

// ---------------- K1: fold Wv across heads, transpose, cast bf16 -----------
// WtB[d][k] = f2b( (1/8) sum_h Wv[k][h*128+d] ),  bmean[d] = (1/8) sum_h bv[.]
__global__ __launch_bounds__(256) void fold_w(
    const float* __restrict__ Wv, const float* __restrict__ bv,
    unsigned short* __restrict__ WtB, float* __restrict__ bmean)
{
  int idx = blockIdx.x * 256 + threadIdx.x;    // 32768 = 256k x 128d
  int k = idx >> 7;
  int d = idx & 127;
  float s = 0.f;
  #pragma unroll
  for (int h = 0; h < HEADS; ++h) s += Wv[(size_t)k * HD + h * DH + d];
  WtB[d * IN_CH + k] = f2b(0.125f * s);
  if (idx < DH) {
    float b = 0.f;
    #pragma unroll
    for (int h = 0; h < HEADS; ++h) b += bv[h * DH + idx];
    bmean[idx] = 0.125f * b;
  }
}

// ---------------- K2: out = X_s @ Wmean + bmean ----------------------------
// 64-row x 128-col tiles, grid.x = 782. 4 waves; wave w owns rows
// [w*16, w*16+16) x all 128 cols: acc[8] of 16x16 tiles.
__global__ __launch_bounds__(256) void gemm_out(
    const float* __restrict__ X, const unsigned short* __restrict__ WtB,
    const float* __restrict__ bmean, float* __restrict__ out)
{
  const int m0   = blockIdx.x * 64;
  const int tid  = threadIdx.x;
  const int wave = tid >> 6, lane = tid & 63;
  const int quad = lane >> 4, l15 = lane & 15;
  const int wr   = wave * 16;            // wave's row offset in tile

  __shared__ __align__(16) unsigned short As[64 * LDS_K];   // X tile -> bf16
  __shared__ __align__(16) unsigned short Bs[128 * LDS_K];  // Wmean^T chunk

  floatx4 acc[8];
  #pragma unroll
  for (int t = 0; t < 8; ++t) acc[t] = (floatx4){0.f, 0.f, 0.f, 0.f};

  // A staging coords: 64 rows x 64 k = 4096 elts, 16/thread.
  const int arow = tid >> 2;             // 0..63
  const int akk  = (tid & 3) * 16;       // 0,16,32,48
  // B staging coords: 128 d x 64 k = 8192 elts, 32/thread.
  const int brow = tid >> 1;             // 0..127
  const int bkk  = (tid & 1) * 32;       // 0,32

  for (int k0 = 0; k0 < IN_CH; k0 += 64) {
    __syncthreads();   // protect LDS from previous iteration's readers
    // ---- stage A (fp32 -> bf16, 64 B contiguous per thread) ----
    int node = m0 + arow;
    float4 x0 = make_float4(0.f, 0.f, 0.f, 0.f), x1 = x0, x2 = x0, x3 = x0;
    if (node < N_NODES) {
      const float* p = X + (size_t)node * IN_CH + k0 + akk;
      x0 = *(const float4*)p;
      x1 = *(const float4*)(p + 4);
      x2 = *(const float4*)(p + 8);
      x3 = *(const float4*)(p + 12);
    }
    {
      unsigned short t8a[8] = {f2b(x0.x), f2b(x0.y), f2b(x0.z), f2b(x0.w),
                               f2b(x1.x), f2b(x1.y), f2b(x1.z), f2b(x1.w)};
      unsigned short t8b[8] = {f2b(x2.x), f2b(x2.y), f2b(x2.z), f2b(x2.w),
                               f2b(x3.x), f2b(x3.y), f2b(x3.z), f2b(x3.w)};
      *(uint4*)&As[arow * LDS_K + akk]     = *(const uint4*)t8a;
      *(uint4*)&As[arow * LDS_K + akk + 8] = *(const uint4*)t8b;
    }
    // ---- stage B (bf16 copy, 64 B contiguous per thread) ----
    {
      const unsigned short* q = WtB + (size_t)brow * IN_CH + k0 + bkk;
      #pragma unroll
      for (int j = 0; j < 4; ++j)
        *(uint4*)&Bs[brow * LDS_K + bkk + j * 8] = *(const uint4*)(q + j * 8);
    }
    __syncthreads();

    // ---- MFMA: 2 K=32 steps x 8 col-tiles ----
    #pragma unroll
    for (int ks = 0; ks < 2; ++ks) {
      shortx8 af = *(const shortx8*)&As[(wr + l15) * LDS_K + ks * 32 + quad * 8];
      #pragma unroll
      for (int tn = 0; tn < 8; ++tn) {
        shortx8 bf = *(const shortx8*)&Bs[(tn * 16 + l15) * LDS_K + ks * 32 + quad * 8];
        acc[tn] = __builtin_amdgcn_mfma_f32_16x16x32_bf16(af, bf, acc[tn], 0, 0, 0);
      }
    }
  }

  // Epilogue: + bmean, fp32 store.
  // C/D layout (m89-verified): col = lane&15, row = quad*4 + reg.
  #pragma unroll
  for (int tn = 0; tn < 8; ++tn) {
    int d = tn * 16 + l15;
    float bm = bmean[d];
    #pragma unroll
    for (int r = 0; r < 4; ++r) {
      int node = m0 + wr + quad * 4 + r;
      if (node < N_NODES)
        out[(size_t)node * DH + d] = acc[tn][r] + bm;
    }
  }
}

// ---------------- host ----------------
extern "C" void kernel_launch(void* const* d_in, const int* in_sizes, int n_in,
                              void* d_out, int out_size, void* d_ws, size_t ws_size,
                              hipStream_t stream) {
  const float* Xs = (const float*)d_in[1];   // source_input [50000][256] fp32
  const float* Wv = (const float*)d_in[6];   // Wv_w [256][1024] fp32
  const float* bv = (const float*)d_in[7];   // Wv_b [1024] fp32

  char* ws = (char*)d_ws;
  unsigned short* WtB   = (unsigned short*)(ws);            // 64 KB
  float*          bmean = (float*)(ws + 65536);             // 512 B

  if (ws_size < 66048) {
    fprintf(stderr, "[TransConv] ws_size=%zu too small\n", ws_size);
    return;
  }

  fold_w<<<128, 256, 0, stream>>>(Wv, bv, WtB, bmean);
  gemm_out<<<782, 256, 0, stream>>>(Xs, WtB, bmean, (float*)d_out);
}